// Round 1
// 830.111 us; speedup vs baseline: 1.2787x; 1.2787x over previous
//
#include <hip/hip_runtime.h>
#include <hip/hip_bf16.h>

#define HDIM 256
#define NEG_SLOPE 0.2f
#define NB 128          // blocks for hist/scatter
#define SLICES 8        // edge slices per dst in the big-degree aggregator
#define TBN 64
#define TBK 32
#define PITCH 40

typedef __attribute__((ext_vector_type(8))) short bf16x8;
typedef __attribute__((ext_vector_type(4))) float f32x4;

// split-bf16 "plane": uint = hi | (lo<<16), x ~= bf16(hi) + bf16(lo)
__device__ inline uint f2pl(float x) {
  __hip_bfloat16 h = __float2bfloat16(x);
  ushort hi = *(ushort*)&h;
  float r = x - __bfloat162float(h);
  __hip_bfloat16 l = __float2bfloat16(r);
  ushort lo = *(ushort*)&l;
  return (uint)hi | ((uint)lo << 16);
}
__device__ inline float pl2f(uint p) {
  ushort hi = (ushort)(p & 0xffff), lo = (ushort)(p >> 16);
  return __bfloat162float(*(__hip_bfloat16*)&hi) + __bfloat162float(*(__hip_bfloat16*)&lo);
}
__device__ inline ushort f2b(float x) {
  __hip_bfloat16 h = __float2bfloat16(x);
  return *(ushort*)&h;
}
__device__ inline float b2f(ushort u) {
  uint x = ((uint)u) << 16;
  return __int_as_float((int)x);
}

static inline int cdiv(int a, int b) { return (a + b - 1) / b; }

// ---------------------------------------------------------------- utilities
__global__ void fillf_kernel(float* __restrict__ p, float v, int n) {
  int i = blockIdx.x * blockDim.x + threadIdx.x;
  if (i < n) p[i] = v;
}

// W[K][N] fp32 -> WT[N][K] planes
__global__ void wconv_kernel(const float* __restrict__ W, uint* __restrict__ WT,
                             int K, int N) {
  int i = blockIdx.x * 256 + threadIdx.x;
  if (i >= K * N) return;
  int k = i / N, n = i - k * N;
  WT[(size_t)n * K + k] = f2pl(W[i]);
}

__global__ void f32_to_b16_kernel(const float* __restrict__ in, ushort* __restrict__ out, int n) {
  int i = blockIdx.x * 256 + threadIdx.x;
  if (i < n) out[i] = f2b(in[i]);
}

// wv[b][k] = sum_n W[k][n]*a[n]  (the folded attention vector W @ a)
// block b: l = b/6; r = b%6; type = r>>1 (pp,dp,cp); isdst = r&1
__global__ __launch_bounds__(256) void matvec_all_kernel(
    const float* __restrict__ Wpp, const float* __restrict__ aspp, const float* __restrict__ adpp,
    const float* __restrict__ Wdp, const float* __restrict__ asdp, const float* __restrict__ addp,
    const float* __restrict__ Wcp, const float* __restrict__ ascp, const float* __restrict__ adcp,
    float* __restrict__ wv) {
  int b = blockIdx.x;
  int l = b / 6, r = b - l * 6, type = r >> 1, isd = r & 1;
  const float* W = (type == 0 ? Wpp : type == 1 ? Wdp : Wcp) + (size_t)l * HDIM * HDIM;
  const float* a = (type == 0 ? (isd ? adpp : aspp)
                  : type == 1 ? (isd ? addp : asdp)
                              : (isd ? adcp : ascp)) + (size_t)l * HDIM;
  int k = threadIdx.x;
  const float4* Wr = (const float4*)(W + (size_t)k * HDIM);
  float s = 0.f;
#pragma unroll 8
  for (int n4 = 0; n4 < HDIM / 4; ++n4) {
    float4 w = Wr[n4];
    float4 av = *(const float4*)(a + n4 * 4);
    s += w.x * av.x + w.y * av.y + w.z * av.z + w.w * av.w;
  }
  wv[(size_t)b * HDIM + k] = s;
}

// ---------------------------------------------------------------- MFMA GEMM
// C = act(A@B + bias). B pre-transposed planes [N][K].
// AMODE: 0 planes A; 1 fp32 A; 2 gathered planes (head W1).
// OUTMODE: 0 fp32 C; 1 plane C.
template <int TBM_, int AMODE, int OUTMODE, int ACT>
__global__ __launch_bounds__(256) void mfma_gemm(
    const void* __restrict__ Av,
    const uint* __restrict__ xdn_pl, const uint* __restrict__ xcn_pl,
    const int* __restrict__ g1, const int* __restrict__ g2, const int* __restrict__ g3,
    int row0,
    const uint* __restrict__ BT, const float* __restrict__ bias,
    void* __restrict__ Cv, int M, int N, int K) {
  __shared__ ushort Ah[TBM_][PITCH];
  __shared__ ushort Al[TBM_][PITCH];
  __shared__ ushort Bh[TBN][PITCH];
  __shared__ ushort Bl[TBN][PITCH];

  constexpr int TPR = 256 / TBM_;   // threads per A-row
  constexpr int SEG = 32 / TPR;     // elems per thread per k-step
  constexpr int NU = SEG / 4;       // 16B loads per thread
  constexpr int TM = TBM_ / 32;     // 16-row tiles per wave (M dir)

  const int tid = threadIdx.x;
  const int lane = tid & 63;
  const int wid = tid >> 6;
  const int wm = wid & 1, wn = wid >> 1;
  const int l16 = lane & 15;
  const int quad = lane >> 4;
  const int m0 = blockIdx.y * TBM_;
  const int n0 = blockIdx.x * TBN;

  const int am = tid / TPR;
  const int ah = (tid % TPR) * SEG;
  const int bn = tid >> 2;
  const int bq = (tid & 3) * 8;

  f32x4 acc[TM][2];
#pragma unroll
  for (int i = 0; i < TM; ++i)
#pragma unroll
    for (int j = 0; j < 2; ++j) acc[i][j] = (f32x4){0.f, 0.f, 0.f, 0.f};

  for (int k0 = 0; k0 < K; k0 += TBK) {
    __syncthreads();
    {
      int gm = m0 + am;
      if (AMODE == 1) {
        const float* A = (const float*)Av;
        const float* ap = (gm < M) ? A + (size_t)gm * K + k0 + ah : nullptr;
#pragma unroll
        for (int u = 0; u < NU; ++u) {
          float4 v = ap ? *(const float4*)(ap + u * 4) : make_float4(0.f, 0.f, 0.f, 0.f);
          uint p0 = f2pl(v.x), p1 = f2pl(v.y), p2 = f2pl(v.z), p3 = f2pl(v.w);
          ushort4 h = {(ushort)(p0 & 0xffff), (ushort)(p1 & 0xffff), (ushort)(p2 & 0xffff), (ushort)(p3 & 0xffff)};
          ushort4 l = {(ushort)(p0 >> 16), (ushort)(p1 >> 16), (ushort)(p2 >> 16), (ushort)(p3 >> 16)};
          *(ushort4*)&Ah[am][ah + u * 4] = h;
          *(ushort4*)&Al[am][ah + u * 4] = l;
        }
      } else {
        const uint* ap = nullptr;
        if (gm < M) {
          if (AMODE == 2) {
            int bi = row0 + gm;
            int seg = k0 >> 8;
            int idx = (seg == 0) ? g1[bi] : (seg == 1 ? g2[bi] : g3[bi]);
            ap = ((seg == 2) ? xcn_pl : xdn_pl) + (size_t)idx * HDIM + (k0 & 255) + ah;
          } else {
            ap = (const uint*)Av + (size_t)gm * K + k0 + ah;
          }
        }
#pragma unroll
        for (int u = 0; u < NU; ++u) {
          uint4 v = ap ? *(const uint4*)(ap + u * 4) : make_uint4(0, 0, 0, 0);
          ushort4 h = {(ushort)(v.x & 0xffff), (ushort)(v.y & 0xffff), (ushort)(v.z & 0xffff), (ushort)(v.w & 0xffff)};
          ushort4 l = {(ushort)(v.x >> 16), (ushort)(v.y >> 16), (ushort)(v.z >> 16), (ushort)(v.w >> 16)};
          *(ushort4*)&Ah[am][ah + u * 4] = h;
          *(ushort4*)&Al[am][ah + u * 4] = l;
        }
      }
    }
    {
      const uint* bp = BT + (size_t)(n0 + bn) * K + k0 + bq;
#pragma unroll
      for (int u = 0; u < 2; ++u) {
        uint4 v = *(const uint4*)(bp + u * 4);
        ushort4 h = {(ushort)(v.x & 0xffff), (ushort)(v.y & 0xffff), (ushort)(v.z & 0xffff), (ushort)(v.w & 0xffff)};
        ushort4 l = {(ushort)(v.x >> 16), (ushort)(v.y >> 16), (ushort)(v.z >> 16), (ushort)(v.w >> 16)};
        *(ushort4*)&Bh[bn][bq + u * 4] = h;
        *(ushort4*)&Bl[bn][bq + u * 4] = l;
      }
    }
    __syncthreads();

    bf16x8 ahf[TM], alf[TM], bhf[2], blf[2];
#pragma unroll
    for (int t = 0; t < TM; ++t) {
      int r = wm * (TBM_ / 2) + t * 16 + l16;
      ahf[t] = *(const bf16x8*)&Ah[r][quad * 8];
      alf[t] = *(const bf16x8*)&Al[r][quad * 8];
    }
#pragma unroll
    for (int t = 0; t < 2; ++t) {
      int r = wn * 32 + t * 16 + l16;
      bhf[t] = *(const bf16x8*)&Bh[r][quad * 8];
      blf[t] = *(const bf16x8*)&Bl[r][quad * 8];
    }
#pragma unroll
    for (int tm = 0; tm < TM; ++tm)
#pragma unroll
      for (int tn = 0; tn < 2; ++tn) {
        acc[tm][tn] = __builtin_amdgcn_mfma_f32_16x16x32_bf16(ahf[tm], bhf[tn], acc[tm][tn], 0, 0, 0);
        acc[tm][tn] = __builtin_amdgcn_mfma_f32_16x16x32_bf16(ahf[tm], blf[tn], acc[tm][tn], 0, 0, 0);
        acc[tm][tn] = __builtin_amdgcn_mfma_f32_16x16x32_bf16(alf[tm], bhf[tn], acc[tm][tn], 0, 0, 0);
      }
  }

#pragma unroll
  for (int tn = 0; tn < 2; ++tn) {
    int col = n0 + wn * 32 + tn * 16 + l16;
    float bv = bias ? bias[col] : 0.f;
#pragma unroll
    for (int tm = 0; tm < TM; ++tm) {
#pragma unroll
      for (int r = 0; r < 4; ++r) {
        int row = m0 + wm * (TBM_ / 2) + tm * 16 + quad * 4 + r;
        if (row >= M) continue;
        float v = acc[tm][tn][r] + bv;
        if (ACT == 1) v = fmaxf(v, 0.f);
        if (OUTMODE == 1) ((uint*)Cv)[(size_t)row * N + col] = f2pl(v);
        else ((float*)Cv)[(size_t)row * N + col] = v;
      }
    }
  }
}

template <int TBM_, int AMODE, int OUTMODE, int ACT>
static void gemm_launch(hipStream_t s, const void* A,
                        const uint* xdn, const uint* xcn,
                        const int* g1, const int* g2, const int* g3, int row0,
                        const uint* BT, const float* bias, void* C,
                        int M, int N, int K) {
  dim3 g(N / TBN, cdiv(M, TBM_));
  mfma_gemm<TBM_, AMODE, OUTMODE, ACT><<<g, 256, 0, s>>>(A, xdn, xcn, g1, g2, g3, row0, BT, bias, C, M, N, K);
}

// ---------------------------------------------------------------- row dots
__global__ __launch_bounds__(256) void rowdot_kernel(
    const float* __restrict__ H, const float* __restrict__ a,
    float* __restrict__ out, int n) {
  int row = blockIdx.x * 4 + (threadIdx.x >> 6);
  if (row >= n) return;
  int lane = threadIdx.x & 63;
  const float* h = H + (size_t)row * HDIM;
  float s = 0.f;
#pragma unroll
  for (int u = 0; u < 4; ++u) {
    int c = lane + u * 64;
    s += h[c] * a[c];
  }
#pragma unroll
  for (int off = 32; off; off >>= 1) s += __shfl_down(s, off);
  if (lane == 0) out[row] = s;
}

__global__ __launch_bounds__(256) void rowdot2_kernel(
    const float* __restrict__ H, const float* __restrict__ a1, const float* __restrict__ a2,
    float* __restrict__ o1, float* __restrict__ o2, int n) {
  int row = blockIdx.x * 4 + (threadIdx.x >> 6);
  if (row >= n) return;
  int lane = threadIdx.x & 63;
  const float* h = H + (size_t)row * HDIM;
  float s1 = 0.f, s2 = 0.f;
#pragma unroll
  for (int u = 0; u < 4; ++u) {
    int c = lane + u * 64;
    float hv = h[c];
    s1 += hv * a1[c];
    s2 += hv * a2[c];
  }
#pragma unroll
  for (int off = 32; off; off >>= 1) {
    s1 += __shfl_down(s1, off);
    s2 += __shfl_down(s2, off);
  }
  if (lane == 0) { o1[row] = s1; o2[row] = s2; }
}

// ---------------------------------------------------------------- counting sort by dst
__global__ __launch_bounds__(256) void hist_kernel(
    const int* __restrict__ src, const int* __restrict__ dst, int E, int nloops,
    int Nd, int* __restrict__ offs) {
  extern __shared__ int bins[];
  int tot = E + nloops;
  int chunk = (tot + NB - 1) / NB;
  int b = blockIdx.x;
  int s0 = b * chunk, s1 = min(s0 + chunk, tot);
  for (int i = threadIdx.x; i < Nd; i += 256) bins[i] = 0;
  __syncthreads();
  for (int i = s0 + threadIdx.x; i < s1; i += 256) {
    int d = (i < E) ? dst[i] : (i - E);
    atomicAdd(&bins[d], 1);
  }
  __syncthreads();
  for (int i = threadIdx.x; i < Nd; i += 256) offs[(size_t)i * NB + b] = bins[i];
}

__global__ __launch_bounds__(256) void scan_bins_kernel(
    int* __restrict__ offs, int* __restrict__ binsum, int Nd) {
  int d = blockIdx.x * 4 + (threadIdx.x >> 6);
  if (d >= Nd) return;
  int lane = threadIdx.x & 63;
  int* p = offs + (size_t)d * NB;
  int v0 = p[2 * lane], v1 = p[2 * lane + 1];
  int s = v0 + v1;
  int t = s;
#pragma unroll
  for (int o = 1; o < 64; o <<= 1) { int u = __shfl_up(t, o); if (lane >= o) t += u; }
  int excl = t - s;
  p[2 * lane] = excl;
  p[2 * lane + 1] = excl + v0;
  if (lane == 63) binsum[d] = t;
}

__global__ __launch_bounds__(256) void scan_base_kernel(
    const int* __restrict__ binsum, int* __restrict__ rowptr, int Nd) {
  __shared__ int wsum[4];
  __shared__ int carry;
  if (threadIdx.x == 0) carry = 0;
  __syncthreads();
  int lane = threadIdx.x & 63, w = threadIdx.x >> 6;
  for (int t0 = 0; t0 < Nd; t0 += 256) {
    int i = t0 + threadIdx.x;
    int v = (i < Nd) ? binsum[i] : 0;
    int t = v;
#pragma unroll
    for (int o = 1; o < 64; o <<= 1) { int u = __shfl_up(t, o); if (lane >= o) t += u; }
    if (lane == 63) wsum[w] = t;
    __syncthreads();
    int add = carry;
    for (int k = 0; k < w; ++k) add += wsum[k];
    if (i < Nd) rowptr[i] = t - v + add;
    __syncthreads();
    if (threadIdx.x == 0) carry += wsum[0] + wsum[1] + wsum[2] + wsum[3];
    __syncthreads();
  }
  if (threadIdx.x == 0) rowptr[Nd] = carry;
}

__global__ __launch_bounds__(256) void scatter_kernel(
    const int* __restrict__ src, const int* __restrict__ dst, int E, int nloops,
    int Nd, const int* __restrict__ offs, const int* __restrict__ rowptr,
    uint* __restrict__ sd) {
  extern __shared__ int bins[];
  int tot = E + nloops;
  int chunk = (tot + NB - 1) / NB;
  int b = blockIdx.x;
  int s0 = b * chunk, s1 = min(s0 + chunk, tot);
  for (int i = threadIdx.x; i < Nd; i += 256) bins[i] = 0;
  __syncthreads();
  for (int i = s0 + threadIdx.x; i < s1; i += 256) {
    int s_, d_;
    if (i < E) { s_ = src[i]; d_ = dst[i]; }
    else       { s_ = d_ = i - E; }
    int local = atomicAdd(&bins[d_], 1);
    int pos = rowptr[d_] + offs[(size_t)d_ * NB + b] + local;
    sd[pos] = (uint)s_ | ((uint)d_ << 16);
  }
}

// ---------------------------------------------------------------- fused GAT edge phase
// aggregate-then-transform: gather bf16 x rows, softmax-weighted sum, output planes.
__global__ __launch_bounds__(256) void gat_agg_pl(
    const int* __restrict__ rowptr, const uint* __restrict__ sd,
    const float* __restrict__ als, const float* __restrict__ ald,
    const ushort* __restrict__ Xb, uint* __restrict__ agg_pl, int n) {
  int d = blockIdx.x * 4 + (threadIdx.x >> 6);
  if (d >= n) return;
  int lane = threadIdx.x & 63;
  int r0 = rowptr[d], r1 = rowptr[d + 1];
  float aldd = ald[d];
  float dsum = 0.f;
  for (int j = r0 + lane; j < r1; j += 64) {
    float e = als[sd[j] & 0xffff] + aldd;
    e = (e > 0.f) ? e : NEG_SLOPE * e;
    dsum += __expf(e);
  }
#pragma unroll
  for (int o = 32; o; o >>= 1) dsum += __shfl_xor(dsum, o);
  float rden = 1.f / (dsum + 1e-16f);

  float4 acc = make_float4(0.f, 0.f, 0.f, 0.f);
  for (int b = r0; b < r1; b += 64) {
    int j = b + lane;
    float exv = 0.f; int srcv = 0;
    if (j < r1) {
      uint p = sd[j];
      srcv = p & 0xffff;
      float e = als[srcv] + aldd;
      e = (e > 0.f) ? e : NEG_SLOPE * e;
      exv = __expf(e) * rden;
    }
    int cnt = min(64, r1 - b);
    for (int t0 = 0; t0 < cnt; t0 += 8) {
      float cf[8]; int sv[8];
#pragma unroll
      for (int u = 0; u < 8; ++u) {
        cf[u] = __shfl(exv, t0 + u);
        sv[u] = __shfl(srcv, t0 + u);
      }
      ushort4 hv[8];
#pragma unroll
      for (int u = 0; u < 8; ++u)
        hv[u] = *(const ushort4*)(Xb + (size_t)sv[u] * HDIM + lane * 4);
#pragma unroll
      for (int u = 0; u < 8; ++u) {
        acc.x += cf[u] * b2f(hv[u].x);
        acc.y += cf[u] * b2f(hv[u].y);
        acc.z += cf[u] * b2f(hv[u].z);
        acc.w += cf[u] * b2f(hv[u].w);
      }
    }
  }
  uint4 o;
  o.x = f2pl(acc.x); o.y = f2pl(acc.y); o.z = f2pl(acc.z); o.w = f2pl(acc.w);
  *(uint4*)(agg_pl + (size_t)d * HDIM + lane * 4) = o;
}

// high-degree / few-dst graphs (cp): block per (dst, edge-slice); fp32 atomic partials.
__global__ __launch_bounds__(256) void gat_agg_slice(
    const int* __restrict__ rowptr, const uint* __restrict__ sd,
    const float* __restrict__ als, const float* __restrict__ ald,
    const ushort* __restrict__ Xb, float* __restrict__ out32, int n) {
  int d = blockIdx.x / SLICES;
  int sl = blockIdx.x - d * SLICES;
  if (d >= n) return;
  int lane = threadIdx.x & 63, w = threadIdx.x >> 6;
  int r0 = rowptr[d], r1 = rowptr[d + 1];
  float aldd = ald[d];
  float dsum = 0.f;
  for (int j = r0 + threadIdx.x; j < r1; j += 256) {
    float e = als[sd[j] & 0xffff] + aldd;
    e = (e > 0.f) ? e : NEG_SLOPE * e;
    dsum += __expf(e);
  }
#pragma unroll
  for (int o = 32; o; o >>= 1) dsum += __shfl_xor(dsum, o);
  __shared__ float wd[4];
  if (lane == 0) wd[w] = dsum;
  __syncthreads();
  float rden = 1.f / (wd[0] + wd[1] + wd[2] + wd[3] + 1e-16f);
  int deg = r1 - r0;
  int per_b = (deg + SLICES - 1) / SLICES;
  int b0 = r0 + sl * per_b, b1 = min(b0 + per_b, r1);
  int wdeg = b1 - b0;
  if (wdeg <= 0) return;
  int per_w = (wdeg + 3) >> 2;
  int w0 = b0 + w * per_w, w1 = min(w0 + per_w, b1);

  float4 acc = make_float4(0.f, 0.f, 0.f, 0.f);
  for (int b = w0; b < w1; b += 64) {
    int j = b + lane;
    float exv = 0.f; int srcv = 0;
    if (j < w1) {
      uint p = sd[j];
      srcv = p & 0xffff;
      float e = als[srcv] + aldd;
      e = (e > 0.f) ? e : NEG_SLOPE * e;
      exv = __expf(e) * rden;
    }
    int cnt = min(64, w1 - b);
    for (int t0 = 0; t0 < cnt; t0 += 8) {
      float cf[8]; int sv[8];
#pragma unroll
      for (int u = 0; u < 8; ++u) {
        cf[u] = __shfl(exv, t0 + u);
        sv[u] = __shfl(srcv, t0 + u);
      }
      ushort4 hv[8];
#pragma unroll
      for (int u = 0; u < 8; ++u)
        hv[u] = *(const ushort4*)(Xb + (size_t)sv[u] * HDIM + lane * 4);
#pragma unroll
      for (int u = 0; u < 8; ++u) {
        acc.x += cf[u] * b2f(hv[u].x);
        acc.y += cf[u] * b2f(hv[u].y);
        acc.z += cf[u] * b2f(hv[u].z);
        acc.w += cf[u] * b2f(hv[u].w);
      }
    }
  }
  float* o = out32 + (size_t)d * HDIM + lane * 4;
  atomicAdd(o + 0, acc.x); atomicAdd(o + 1, acc.y);
  atomicAdd(o + 2, acc.z); atomicAdd(o + 3, acc.w);
}

// ---------------------------------------------------------------- norms / head
// fp32 in -> l2norm -> fp32 out + bf16 copy (gather table for next layer)
__global__ __launch_bounds__(256) void l2norm_f32b_kernel(
    const float* __restrict__ in, float* __restrict__ outf, ushort* __restrict__ outb, int n) {
  int row = blockIdx.x * 4 + (threadIdx.x >> 6);
  if (row >= n) return;
  int lane = threadIdx.x & 63;
  float v[4];
  float ss = 0.f;
#pragma unroll
  for (int u = 0; u < 4; ++u) {
    float t = in[(size_t)row * HDIM + lane + u * 64];
    v[u] = t; ss += t * t;
  }
#pragma unroll
  for (int off = 32; off; off >>= 1) ss += __shfl_xor(ss, off);
  float sc = 1.0f / fmaxf(sqrtf(ss), 1e-12f);
#pragma unroll
  for (int u = 0; u < 4; ++u) {
    float f = v[u] * sc;
    int c = lane + u * 64;
    outf[(size_t)row * HDIM + c] = f;
    outb[(size_t)row * HDIM + c] = f2b(f);
  }
}

template <int IN_PL>
__global__ __launch_bounds__(256) void l2norm_pl_kernel(
    const void* __restrict__ in, const float* __restrict__ bias,
    uint* __restrict__ out_pl, int n) {
  int row = blockIdx.x * 4 + (threadIdx.x >> 6);
  if (row >= n) return;
  int lane = threadIdx.x & 63;
  float v[4];
  float ss = 0.f;
#pragma unroll
  for (int u = 0; u < 4; ++u) {
    int c = lane + u * 64;
    float t = IN_PL ? pl2f(((const uint*)in)[(size_t)row * HDIM + c])
                    : ((const float*)in)[(size_t)row * HDIM + c];
    if (bias) t += bias[c];
    v[u] = t;
    ss += t * t;
  }
#pragma unroll
  for (int off = 32; off; off >>= 1) ss += __shfl_xor(ss, off);
  float sc = 1.0f / fmaxf(sqrtf(ss), 1e-12f);
#pragma unroll
  for (int u = 0; u < 4; ++u) {
    int c = lane + u * 64;
    out_pl[(size_t)row * HDIM + c] = f2pl(v[u] * sc);
  }
}

__global__ __launch_bounds__(256) void head3_kernel(
    const float* __restrict__ h2, const float* __restrict__ W3, const float* __restrict__ b3,
    float* __restrict__ out, int M, int K) {
  int i = blockIdx.x * 4 + (threadIdx.x >> 6);
  int lane = threadIdx.x & 63;
  if (i >= M) return;
  float s0 = 0.f, s1 = 0.f;
  for (int k = lane; k < K; k += 64) {
    float h = h2[(size_t)i * K + k];
    s0 += h * W3[k * 2 + 0];
    s1 += h * W3[k * 2 + 1];
  }
#pragma unroll
  for (int off = 32; off; off >>= 1) {
    s0 += __shfl_down(s0, off);
    s1 += __shfl_down(s1, off);
  }
  if (lane == 0) {
    out[(size_t)i * 2 + 0] = s0 + b3[0];
    out[(size_t)i * 2 + 1] = s1 + b3[1];
  }
}

// ---------------------------------------------------------------- host side
static void build_sorted(hipStream_t stream,
                         const int* src, const int* dst, int E, int nloops, int Nd,
                         int* offs, int* binsum, int* rowptr, uint* sd) {
  size_t lds = (size_t)Nd * sizeof(int);
  hist_kernel<<<NB, 256, lds, stream>>>(src, dst, E, nloops, Nd, offs);
  scan_bins_kernel<<<cdiv(Nd, 4), 256, 0, stream>>>(offs, binsum, Nd);
  scan_base_kernel<<<1, 256, 0, stream>>>(binsum, rowptr, Nd);
  scatter_kernel<<<NB, 256, lds, stream>>>(src, dst, E, nloops, Nd, offs, rowptr, sd);
}

extern "C" void kernel_launch(void* const* d_in, const int* in_sizes, int n_in,
                              void* d_out, int out_size, void* d_ws, size_t ws_size,
                              hipStream_t stream) {
  const float* drug_emb = (const float*)d_in[0];
  const float* prot_emb = (const float*)d_in[1];
  const float* cell_emb = (const float*)d_in[2];
  const float* W_pp = (const float*)d_in[3];
  const float* as_pp = (const float*)d_in[4];
  const float* ad_pp = (const float*)d_in[5];
  const float* b_pp = (const float*)d_in[6];
  const float* W_dp = (const float*)d_in[7];
  const float* as_dp = (const float*)d_in[8];
  const float* ad_dp = (const float*)d_in[9];
  const float* b_dp = (const float*)d_in[10];
  const float* W_cp = (const float*)d_in[11];
  const float* as_cp = (const float*)d_in[12];
  const float* ad_cp = (const float*)d_in[13];
  const float* b_cp = (const float*)d_in[14];
  const float* W1 = (const float*)d_in[15];
  const float* b1 = (const float*)d_in[16];
  const float* W2 = (const float*)d_in[17];
  const float* b2 = (const float*)d_in[18];
  const float* W3 = (const float*)d_in[19];
  const float* b3 = (const float*)d_in[20];
  const int* edge_pp = (const int*)d_in[21];
  const int* edge_dp = (const int*)d_in[22];
  const int* edge_cp = (const int*)d_in[23];
  const int* drug1 = (const int*)d_in[24];
  const int* drug2 = (const int*)d_in[25];
  const int* cellb = (const int*)d_in[26];

  const int ND = in_sizes[0] / HDIM;   // 2000
  const int NP = in_sizes[1] / HDIM;   // 19000
  const int NC = in_sizes[2] / HDIM;   // 100
  const int L = in_sizes[3] / (HDIM * HDIM);  // 2
  const int E_pp = in_sizes[21] / 2;
  const int E_dp = in_sizes[22] / 2;
  const int E_cp = in_sizes[23] / 2;
  const int B = in_sizes[24];          // 8192
  (void)n_in; (void)out_size;

  const int* src_pp = edge_pp;          const int* dst_pp = edge_pp + E_pp;
  const int* src_dp = edge_dp;          const int* dst_dp = edge_dp + E_dp;
  const int* src_cp = edge_cp;          const int* dst_cp = edge_cp + E_cp;
  const int tot_pp = E_pp + NP, tot_dp = E_dp, tot_cp = E_cp;
  int maxN = NP > ND ? NP : ND; if (NC > maxN) maxN = NC;

  // ---------------- workspace
  char* wsb = (char*)d_ws;
  size_t off = 0;
  auto alloc = [&](size_t bytes) -> void* {
    void* p = wsb + off;
    off += (bytes + 255) & ~(size_t)255;
    return p;
  };

  float* Xp  = (float*)alloc((size_t)NP * HDIM * 4);    // protein state fp32 (rowdots)
  ushort* Xpb = (ushort*)alloc((size_t)NP * HDIM * 2);  // protein state bf16 (gather)
  float* Xd  = (float*)alloc((size_t)ND * HDIM * 4);
  float* Xc  = (float*)alloc((size_t)NC * HDIM * 4);
  uint* xdn_pl = (uint*)alloc((size_t)ND * HDIM * 4);
  uint* xcn_pl = (uint*)alloc((size_t)NC * HDIM * 4);
  uint* WTpp = (uint*)alloc((size_t)L * HDIM * HDIM * 4);
  uint* WTdp = (uint*)alloc((size_t)L * HDIM * HDIM * 4);
  uint* WTcp = (uint*)alloc((size_t)L * HDIM * HDIM * 4);
  float* wv  = (float*)alloc((size_t)L * 6 * HDIM * 4); // folded W@a vectors
  float* als1 = (float*)alloc((size_t)maxN * 4);
  float* als2 = (float*)alloc((size_t)maxN * 4);
  float* ald1 = (float*)alloc((size_t)maxN * 4);
  float* ald2 = (float*)alloc((size_t)maxN * 4);
  int* binsum = (int*)alloc((size_t)maxN * 4);
  int* rp_pp = (int*)alloc((size_t)(NP + 1) * 4);
  int* rp_dp = (int*)alloc((size_t)(ND + 1) * 4);
  int* rp_cp = (int*)alloc((size_t)(NC + 1) * 4);
  uint* sd_pp = (uint*)alloc((size_t)tot_pp * 4);
  uint* sd_dp = (uint*)alloc((size_t)tot_dp * 4);
  uint* sd_cp = (uint*)alloc((size_t)tot_cp * 4);
  float* out32 = (float*)alloc((size_t)NC * HDIM * 4);  // cp partial accumulator
  size_t S0 = off;

  // scratch S overlays: [offs] -> [agg_pl | tmp] -> [W1T|W2T|h1|h2]
  int* offs = (int*)(wsb + S0);
  build_sorted(stream, src_pp, dst_pp, E_pp, NP, NP, offs, binsum, rp_pp, sd_pp);
  build_sorted(stream, src_dp, dst_dp, E_dp, 0, ND, offs, binsum, rp_dp, sd_dp);
  build_sorted(stream, src_cp, dst_cp, E_cp, 0, NC, offs, binsum, rp_cp, sd_cp);

  // ---- weight planes (transposed) + folded attention vectors + initial bf16 x_p
  for (int l = 0; l < L; ++l) {
    int WOFF = l * HDIM * HDIM;
    wconv_kernel<<<cdiv(HDIM * HDIM, 256), 256, 0, stream>>>(W_pp + WOFF, WTpp + WOFF, HDIM, HDIM);
    wconv_kernel<<<cdiv(HDIM * HDIM, 256), 256, 0, stream>>>(W_dp + WOFF, WTdp + WOFF, HDIM, HDIM);
    wconv_kernel<<<cdiv(HDIM * HDIM, 256), 256, 0, stream>>>(W_cp + WOFF, WTcp + WOFF, HDIM, HDIM);
  }
  matvec_all_kernel<<<L * 6, 256, 0, stream>>>(W_pp, as_pp, ad_pp, W_dp, as_dp, ad_dp,
                                               W_cp, as_cp, ad_cp, wv);
  f32_to_b16_kernel<<<cdiv(NP * HDIM, 256), 256, 0, stream>>>(prot_emb, Xpb, NP * HDIM);

  size_t aggB = ((size_t)NP * HDIM * 4 + 255) & ~(size_t)255;
  uint* agg_pl = (uint*)(wsb + S0);
  float* tmp = (float*)(wsb + S0 + aggB);

  for (int l = 0; l < L; ++l) {
    const int WOFF = l * HDIM * HDIM, VOFF = l * HDIM;
    const float* wvl = wv + (size_t)l * 6 * HDIM;
    const float* Xp_cur = (l == 0) ? prot_emb : Xp;
    const float* Xd_cur = (l == 0) ? drug_emb : Xd;
    const float* Xc_cur = (l == 0) ? cell_emb : Xc;

    // ---- p-p: attention logits -> aggregate x -> transform -> l2norm
    rowdot2_kernel<<<cdiv(NP, 4), 256, 0, stream>>>(Xp_cur, wvl + 0 * HDIM, wvl + 1 * HDIM,
                                                    als1, ald1, NP);
    gat_agg_pl<<<cdiv(NP, 4), 256, 0, stream>>>(rp_pp, sd_pp, als1, ald1, Xpb, agg_pl, NP);
    gemm_launch<128, 0, 0, 0>(stream, agg_pl, nullptr, nullptr, nullptr, nullptr, nullptr, 0,
                              WTpp + WOFF, b_pp + VOFF, tmp, NP, HDIM, HDIM);
    l2norm_f32b_kernel<<<cdiv(NP, 4), 256, 0, stream>>>(tmp, Xp, Xpb, NP);

    // ---- rowdots for d-p / c-p on updated x_p (fused pass)
    rowdot2_kernel<<<cdiv(NP, 4), 256, 0, stream>>>(Xp, wvl + 2 * HDIM, wvl + 4 * HDIM,
                                                    als1, als2, NP);
    rowdot_kernel<<<cdiv(ND, 4), 256, 0, stream>>>(Xd_cur, wvl + 3 * HDIM, ald1, ND);
    rowdot_kernel<<<cdiv(NC, 4), 256, 0, stream>>>(Xc_cur, wvl + 5 * HDIM, ald2, NC);

    // ---- d-p: aggregate then transform (M=ND, not NP)
    gat_agg_pl<<<cdiv(ND, 4), 256, 0, stream>>>(rp_dp, sd_dp, als1, ald1, Xpb, agg_pl, ND);
    gemm_launch<64, 0, 0, 1>(stream, agg_pl, nullptr, nullptr, nullptr, nullptr, nullptr, 0,
                             WTdp + WOFF, b_dp + VOFF, Xd, ND, HDIM, HDIM);

    // ---- c-p: slice-aggregate then transform (M=NC)
    fillf_kernel<<<cdiv(NC * HDIM, 256), 256, 0, stream>>>(out32, 0.f, NC * HDIM);
    gat_agg_slice<<<NC * SLICES, 256, 0, stream>>>(rp_cp, sd_cp, als2, ald2, Xpb, out32, NC);
    gemm_launch<64, 1, 0, 1>(stream, out32, nullptr, nullptr, nullptr, nullptr, nullptr, 0,
                             WTcp + WOFF, b_cp + VOFF, Xc, NC, HDIM, HDIM);
  }

  // ---------------- head
  l2norm_pl_kernel<0><<<cdiv(ND, 4), 256, 0, stream>>>(Xd, nullptr, xdn_pl, ND);
  l2norm_pl_kernel<0><<<cdiv(NC, 4), 256, 0, stream>>>(Xc, nullptr, xcn_pl, NC);

  uint* W1T = (uint*)(wsb + S0);                       // [1536][768]
  uint* W2T = W1T + (size_t)1536 * 768;                // [512][1536]
  uint* h1_pl = W2T + (size_t)512 * 1536;
  size_t wsz = ws_size ? ws_size : ((size_t)1 << 30);
  size_t fixed = S0 + ((size_t)1536 * 768 + (size_t)512 * 1536) * 4;
  int CH = 8192;                                       // one chunk -> 2 blocks/CU on W2
  while (CH > 1024 && fixed + (size_t)CH * (1536 + 512) * 4 > wsz) CH >>= 1;
  float* h2 = (float*)(h1_pl + (size_t)CH * 1536);

  wconv_kernel<<<cdiv(768 * 1536, 256), 256, 0, stream>>>(W1, W1T, 768, 1536);
  wconv_kernel<<<cdiv(1536 * 512, 256), 256, 0, stream>>>(W2, W2T, 1536, 512);

  float* outp = (float*)d_out;
  for (int c0 = 0; c0 < B; c0 += CH) {
    int M = (B - c0) < CH ? (B - c0) : CH;
    gemm_launch<128, 2, 1, 1>(stream, nullptr, xdn_pl, xcn_pl, drug1, drug2, cellb, c0,
                              W1T, b1, h1_pl, M, 1536, 768);
    gemm_launch<128, 0, 0, 1>(stream, h1_pl, nullptr, nullptr, nullptr, nullptr, nullptr, 0,
                              W2T, b2, h2, M, 512, 1536);
    head3_kernel<<<cdiv(M, 4), 256, 0, stream>>>(h2, W3, b3, outp + (size_t)c0 * 2, M, 512);
  }
}